// Round 1
// baseline (1851.817 us; speedup 1.0000x reference)
//
#include <hip/hip_runtime.h>
#include <math.h>

// ---------------------------------------------------------------------------
// GNN: 3x GCNConv(edge-weighted, self-loops) + SiLU, mean-pool per graph, MLP.
// Key identity: aggregate in INPUT feature space, then transform:
//   agg_out = (sum_e norm_e * x[src_e]) @ W   (W is linear over features)
// so scatter dims are 16/16/64 instead of 16/64/256.
// ---------------------------------------------------------------------------

__device__ __forceinline__ float silu_f(float v) { return v / (1.0f + expf(-v)); }

// ---- degree: deg[i] = sum_{e: dst=i} ew[e]  (self-loop +1 added later) ----
__global__ void k_deg(const int* __restrict__ dst, const float* __restrict__ ew,
                      float* __restrict__ deg, int E) {
    int e = blockIdx.x * blockDim.x + threadIdx.x;
    if (e < E) atomicAdd(&deg[dst[e]], ew[e]);
}

// ---- dinv = 1/sqrt(deg+1), recip = 1/(deg+1) ----
__global__ void k_norm(const float* __restrict__ deg, float* __restrict__ dinv,
                       float* __restrict__ recip, int N) {
    int i = blockIdx.x * blockDim.x + threadIdx.x;
    if (i < N) {
        float d = deg[i] + 1.0f;
        dinv[i]  = 1.0f / sqrtf(d);   // precise (no fast-math): ref=np, tol 2e-5 abs
        recip[i] = 1.0f / d;
    }
}

// ---- edge scatter: agg[dst] += h[src] * (dinv[src]*ew*dinv[dst]) ----
// thread = (edge, dim). One wave covers 64/D edges; atomics are a single
// wave-wide global_atomic_add covering D consecutive dwords per edge row.
template <int D>
__global__ void k_scatter(const float* __restrict__ h, const int* __restrict__ src,
                          const int* __restrict__ dst, const float* __restrict__ ew,
                          const float* __restrict__ dinv, float* __restrict__ agg, int E) {
    int tid = blockIdx.x * blockDim.x + threadIdx.x;
    int e = tid / D;
    int d = tid & (D - 1);
    if (e >= E) return;
    int s = src[e], t = dst[e];
    float nrm = dinv[s] * ew[e] * dinv[t];
    atomicAdd(&agg[t * D + d], h[s * D + d] * nrm);
}

// ---- layer 1 transform: h1 = silu((agg + x*recip) @ W1 + b1), 16->16 ----
__global__ void k_xform1(const float* __restrict__ x, const float* __restrict__ agg,
                         const float* __restrict__ recip, const float* __restrict__ W,
                         const float* __restrict__ b, float* __restrict__ out, int N) {
    __shared__ float Ws[16 * 16];
    __shared__ float bs[16];
    if (threadIdx.x < 16 * 16) Ws[threadIdx.x] = W[threadIdx.x];
    if (threadIdx.x < 16) bs[threadIdx.x] = b[threadIdx.x];
    __syncthreads();
    int n = blockIdx.x * blockDim.x + threadIdx.x;
    if (n >= N) return;
    float r = recip[n];
    float y[16];
    const float4* x4 = (const float4*)(x + n * 16);
    const float4* a4 = (const float4*)(agg + n * 16);
#pragma unroll
    for (int j = 0; j < 4; j++) {
        float4 xv = x4[j], av = a4[j];
        y[4 * j + 0] = av.x + xv.x * r;
        y[4 * j + 1] = av.y + xv.y * r;
        y[4 * j + 2] = av.z + xv.z * r;
        y[4 * j + 3] = av.w + xv.w * r;
    }
    float4* o4 = (float4*)(out + n * 16);
#pragma unroll
    for (int oc = 0; oc < 4; oc++) {
        float4 acc = make_float4(bs[oc * 4 + 0], bs[oc * 4 + 1], bs[oc * 4 + 2], bs[oc * 4 + 3]);
#pragma unroll
        for (int d = 0; d < 16; d++) {
            float yd = y[d];
            acc.x += yd * Ws[d * 16 + oc * 4 + 0];
            acc.y += yd * Ws[d * 16 + oc * 4 + 1];
            acc.z += yd * Ws[d * 16 + oc * 4 + 2];
            acc.w += yd * Ws[d * 16 + oc * 4 + 3];
        }
        acc.x = silu_f(acc.x); acc.y = silu_f(acc.y);
        acc.z = silu_f(acc.z); acc.w = silu_f(acc.w);
        o4[oc] = acc;
    }
}

// ---- layer 2 transform: h2 = silu((agg + h1*recip) @ W2 + b2), 16->64 ----
__global__ void k_xform2(const float* __restrict__ h, const float* __restrict__ agg,
                         const float* __restrict__ recip, const float* __restrict__ W,
                         const float* __restrict__ b, float* __restrict__ out, int N) {
    __shared__ float Ws[16 * 64];
    __shared__ float bs[64];
    for (int i = threadIdx.x; i < 16 * 64; i += blockDim.x) Ws[i] = W[i];
    if (threadIdx.x < 64) bs[threadIdx.x] = b[threadIdx.x];
    __syncthreads();
    int n = blockIdx.x * blockDim.x + threadIdx.x;
    if (n >= N) return;
    float r = recip[n];
    float y[16];
    const float4* h4 = (const float4*)(h + n * 16);
    const float4* a4 = (const float4*)(agg + n * 16);
#pragma unroll
    for (int j = 0; j < 4; j++) {
        float4 hv = h4[j], av = a4[j];
        y[4 * j + 0] = av.x + hv.x * r;
        y[4 * j + 1] = av.y + hv.y * r;
        y[4 * j + 2] = av.z + hv.z * r;
        y[4 * j + 3] = av.w + hv.w * r;
    }
    float4* o4 = (float4*)(out + (long long)n * 64);
#pragma unroll
    for (int oc = 0; oc < 16; oc++) {
        float4 acc = make_float4(bs[oc * 4 + 0], bs[oc * 4 + 1], bs[oc * 4 + 2], bs[oc * 4 + 3]);
#pragma unroll
        for (int d = 0; d < 16; d++) {
            float yd = y[d];
            acc.x += yd * Ws[d * 64 + oc * 4 + 0];
            acc.y += yd * Ws[d * 64 + oc * 4 + 1];
            acc.z += yd * Ws[d * 64 + oc * 4 + 2];
            acc.w += yd * Ws[d * 64 + oc * 4 + 3];
        }
        acc.x = silu_f(acc.x); acc.y = silu_f(acc.y);
        acc.z = silu_f(acc.z); acc.w = silu_f(acc.w);
        o4[oc] = acc;
    }
}

// ---- layer 3 transform: h3 = silu((agg + h2*recip) @ W3 + b3), 64->256 ----
// Wave per node: lane holds y[lane]; __shfl broadcasts y_k; W3 staged in LDS
// as float4 rows so each lane does ds_read_b128 for its 4 output cols.
__global__ __launch_bounds__(256) void k_xform3(const float* __restrict__ h,
                                                const float* __restrict__ agg,
                                                const float* __restrict__ recip,
                                                const float* __restrict__ W,
                                                const float* __restrict__ b,
                                                float* __restrict__ out, int N) {
    __shared__ float4 Ws[64 * 64];  // [k][lane] -> W3[k*256 + lane*4 .. +3]  (64 KiB)
    for (int i = threadIdx.x; i < 64 * 64; i += 256) Ws[i] = ((const float4*)W)[i];
    __syncthreads();
    int wave = threadIdx.x >> 6;
    int lane = threadIdx.x & 63;
    float4 bv = ((const float4*)b)[lane];
    for (int base = blockIdx.x * 4; base < N; base += gridDim.x * 4) {
        int n = base + wave;
        if (n >= N) continue;  // wave-uniform
        float r = recip[n];
        float yv = agg[n * 64 + lane] + h[n * 64 + lane] * r;
        float4 acc = bv;
#pragma unroll
        for (int k = 0; k < 64; k++) {
            float yk = __shfl(yv, k, 64);
            float4 w = Ws[k * 64 + lane];
            acc.x += yk * w.x; acc.y += yk * w.y;
            acc.z += yk * w.z; acc.w += yk * w.w;
        }
        acc.x = silu_f(acc.x); acc.y = silu_f(acc.y);
        acc.z = silu_f(acc.z); acc.w = silu_f(acc.w);
        ((float4*)(out + (long long)n * 256))[lane] = acc;
    }
}

// ---- mean-pool per graph (batch sorted -> binary search range; IN-ORDER sum
// matches numpy segment_sum rounding) + 3-layer MLP, one block per graph ----
__global__ __launch_bounds__(256) void k_pool_mlp(const float* __restrict__ h3,
                                                  const int* __restrict__ batch, int N,
                                                  const float* __restrict__ L1,
                                                  const float* __restrict__ c1,
                                                  const float* __restrict__ L2,
                                                  const float* __restrict__ c2,
                                                  const float* __restrict__ L3,
                                                  const float* __restrict__ c3,
                                                  float* __restrict__ out) {
    __shared__ float pooled[256];
    __shared__ float z1[128];
    __shared__ float z2[64];
    int g = blockIdx.x;
    // lower_bound(batch, g) and lower_bound(batch, g+1)
    int lo = 0, hi = N;
    while (lo < hi) { int m = (lo + hi) >> 1; if (batch[m] < g) lo = m + 1; else hi = m; }
    int start = lo;
    hi = N;
    while (lo < hi) { int m = (lo + hi) >> 1; if (batch[m] < g + 1) lo = m + 1; else hi = m; }
    int end = lo;
    int t = threadIdx.x;
    float s = 0.0f;
    for (int i = start; i < end; i++) s += h3[(long long)i * 256 + t];
    int cnt = end - start;
    pooled[t] = s / (float)(cnt > 0 ? cnt : 1);
    __syncthreads();
    if (t < 128) {
        float acc = c1[t];
        for (int k = 0; k < 256; k++) acc += pooled[k] * L1[k * 128 + t];
        z1[t] = silu_f(acc);
    }
    __syncthreads();
    if (t < 64) {
        float acc = c2[t];
        for (int k = 0; k < 128; k++) acc += z1[k] * L2[k * 64 + t];
        z2[t] = silu_f(acc);
    }
    __syncthreads();
    if (t < 3) {
        float acc = c3[t];
        for (int k = 0; k < 64; k++) acc += z2[k] * L3[k * 3 + t];
        out[g * 3 + t] = acc;
    }
}

extern "C" void kernel_launch(void* const* d_in, const int* in_sizes, int n_in,
                              void* d_out, int out_size, void* d_ws, size_t ws_size,
                              hipStream_t stream) {
    const float* x     = (const float*)d_in[0];
    const int*   ei    = (const int*)d_in[1];
    const float* ea    = (const float*)d_in[2];
    const int*   batch = (const int*)d_in[3];
    const float* W1 = (const float*)d_in[4];
    const float* b1 = (const float*)d_in[5];
    const float* W2 = (const float*)d_in[6];
    const float* b2 = (const float*)d_in[7];
    const float* W3 = (const float*)d_in[8];
    const float* b3 = (const float*)d_in[9];
    const float* L1 = (const float*)d_in[10];
    const float* c1 = (const float*)d_in[11];
    const float* L2 = (const float*)d_in[12];
    const float* c2 = (const float*)d_in[13];
    const float* L3 = (const float*)d_in[14];
    const float* c3 = (const float*)d_in[15];
    float* out = (float*)d_out;

    const int N = in_sizes[0] / 16;
    const int E = in_sizes[2];
    const int G = out_size / 3;
    const int* src = ei;
    const int* dst = ei + E;

    char* ws = (char*)d_ws;
    size_t off = 0;
    auto alloc = [&](size_t bytes) -> float* {
        float* p = (float*)(ws + off);
        off += (bytes + 255) & ~(size_t)255;
        return p;
    };
    float* deg   = alloc((size_t)N * 4);
    float* dinv  = alloc((size_t)N * 4);
    float* recip = alloc((size_t)N * 4);
    float* agg   = alloc((size_t)N * 64 * 4);   // reused across layers (max in-dim 64)
    float* h1    = alloc((size_t)N * 16 * 4);
    float* h2    = alloc((size_t)N * 64 * 4);
    float* h3    = alloc((size_t)N * 256 * 4);
    (void)ws_size;

    // degree + norms (shared across all 3 layers)
    hipMemsetAsync(deg, 0, (size_t)N * 4, stream);
    k_deg<<<(E + 255) / 256, 256, 0, stream>>>(dst, ea, deg, E);
    k_norm<<<(N + 255) / 256, 256, 0, stream>>>(deg, dinv, recip, N);

    // layer 1 (propagate x in 16-dim space, then 16->16 transform)
    hipMemsetAsync(agg, 0, (size_t)N * 16 * 4, stream);
    k_scatter<16><<<((size_t)E * 16 + 255) / 256, 256, 0, stream>>>(x, src, dst, ea, dinv, agg, E);
    k_xform1<<<(N + 255) / 256, 256, 0, stream>>>(x, agg, recip, W1, b1, h1, N);

    // layer 2 (propagate h1 in 16-dim space, then 16->64 transform)
    hipMemsetAsync(agg, 0, (size_t)N * 16 * 4, stream);
    k_scatter<16><<<((size_t)E * 16 + 255) / 256, 256, 0, stream>>>(h1, src, dst, ea, dinv, agg, E);
    k_xform2<<<(N + 255) / 256, 256, 0, stream>>>(h1, agg, recip, W2, b2, h2, N);

    // layer 3 (propagate h2 in 64-dim space, then 64->256 transform)
    hipMemsetAsync(agg, 0, (size_t)N * 64 * 4, stream);
    k_scatter<64><<<((size_t)E * 64 + 255) / 256, 256, 0, stream>>>(h2, src, dst, ea, dinv, agg, E);
    k_xform3<<<2048, 256, 0, stream>>>(h2, agg, recip, W3, b3, h3, N);

    // mean-pool + MLP head
    k_pool_mlp<<<G, 256, 0, stream>>>(h3, batch, N, L1, c1, L2, c2, L3, c3, out);
}

// Round 2
// 1398.530 us; speedup vs baseline: 1.3241x; 1.3241x over previous
//
#include <hip/hip_runtime.h>
#include <math.h>

// ---------------------------------------------------------------------------
// GNN: 3x GCNConv(edge-weighted, self-loops) + SiLU, mean-pool, MLP.
// R1 change: replace atomic scatters (800MB HBM RMW on layer-3 alone) with
// device-built CSR-by-dst + gather kernels (pure streaming reads, tiny writes).
// agg[n] = dinv[n] * sum_{e: dst=n} (ew_e * dinv[src_e]) * h[src_e]
// ---------------------------------------------------------------------------

__device__ __forceinline__ float silu_f(float v) { return v / (1.0f + expf(-v)); }

// ---- deg (weighted, atomic) + integer in-degree count, one pass over edges ----
__global__ void k_deg_count(const int* __restrict__ dst, const float* __restrict__ ew,
                            float* __restrict__ deg, int* __restrict__ cnt, int E) {
    int e = blockIdx.x * blockDim.x + threadIdx.x;
    if (e < E) {
        int t = dst[e];
        atomicAdd(&deg[t], ew[e]);
        atomicAdd(&cnt[t], 1);
    }
}

// ---- dinv = 1/sqrt(deg+1), recip = 1/(deg+1) ----
__global__ void k_norm(const float* __restrict__ deg, float* __restrict__ dinv,
                       float* __restrict__ recip, int N) {
    int i = blockIdx.x * blockDim.x + threadIdx.x;
    if (i < N) {
        float d = deg[i] + 1.0f;
        dinv[i]  = 1.0f / sqrtf(d);
        recip[i] = 1.0f / d;
    }
}

// ---- exclusive scan of cnt -> offs (3-kernel: block scan, scan of sums, add) ----
__global__ void k_scan1(const int* __restrict__ cnt, int* __restrict__ offs,
                        int* __restrict__ bsums, int N) {
    __shared__ int tmp[256];
    int t = threadIdx.x;
    int i = blockIdx.x * 256 + t;
    int v = (i < N) ? cnt[i] : 0;
    tmp[t] = v;
    __syncthreads();
#pragma unroll
    for (int o = 1; o < 256; o <<= 1) {
        int x = (t >= o) ? tmp[t - o] : 0;
        __syncthreads();
        tmp[t] += x;
        __syncthreads();
    }
    if (i < N) offs[i] = tmp[t] - v;         // exclusive within block
    if (t == 255) bsums[blockIdx.x] = tmp[t]; // block total
}

__global__ void k_scan2(int* __restrict__ bsums, int nb) {
    __shared__ int tmp[512];
    int t = threadIdx.x;
    int v = (t < nb) ? bsums[t] : 0;
    tmp[t] = v;
    __syncthreads();
#pragma unroll
    for (int o = 1; o < 512; o <<= 1) {
        int x = (t >= o) ? tmp[t - o] : 0;
        __syncthreads();
        tmp[t] += x;
        __syncthreads();
    }
    if (t < nb) bsums[t] = tmp[t] - v;       // exclusive block offsets (in place)
}

__global__ void k_scan3(int* __restrict__ offs, const int* __restrict__ bsums,
                        int N, int E) {
    int i = blockIdx.x * blockDim.x + threadIdx.x;
    if (i < N) offs[i] += bsums[i >> 8];
    if (i == N) offs[N] = E;
}

// ---- fill CSR: csr[p] = (src, ew*dinv[src]) packed; cursors pre-copied from offs ----
__global__ void k_fill(const int* __restrict__ src, const int* __restrict__ dst,
                       const float* __restrict__ ew, const float* __restrict__ dinv,
                       int* __restrict__ cursors, int2* __restrict__ csr, int E) {
    int e = blockIdx.x * blockDim.x + threadIdx.x;
    if (e >= E) return;
    int t = dst[e];
    int p = atomicAdd(&cursors[t], 1);
    int s = src[e];
    float w = ew[e] * dinv[s];               // dinv[dst] factored out in gather
    csr[p] = make_int2(s, __float_as_int(w));
}

// ---- gather D=16: wave per node; lanes split into 4 edge-groups x 16 dims ----
__global__ __launch_bounds__(256) void k_gather16(const float* __restrict__ h,
                                                  const int2* __restrict__ csr,
                                                  const int* __restrict__ offs,
                                                  const float* __restrict__ dinv,
                                                  float* __restrict__ agg, int N) {
    int n = blockIdx.x * 4 + (threadIdx.x >> 6);
    if (n >= N) return;                      // wave-uniform
    int lane = threadIdx.x & 63;
    int d = lane & 15, eg = lane >> 4;
    int p0 = offs[n], p1 = offs[n + 1];
    float acc = 0.0f;
    for (int p = p0 + eg; p < p1; p += 4) {
        int2 ent = csr[p];
        acc += __int_as_float(ent.y) * h[ent.x * 16 + d];
    }
    acc += __shfl_down(acc, 32, 64);
    acc += __shfl_down(acc, 16, 64);
    if (lane < 16) agg[n * 16 + lane] = acc * dinv[n];
}

// ---- gather D=64: wave per node; lane = dim; 4 edges/iter for MLP of loads ----
__global__ __launch_bounds__(256) void k_gather64(const float* __restrict__ h,
                                                  const int2* __restrict__ csr,
                                                  const int* __restrict__ offs,
                                                  const float* __restrict__ dinv,
                                                  float* __restrict__ agg, int N) {
    int n = blockIdx.x * 4 + (threadIdx.x >> 6);
    if (n >= N) return;                      // wave-uniform
    int lane = threadIdx.x & 63;
    int p0 = offs[n], p1 = offs[n + 1];
    float acc = 0.0f;
    int p = p0;
    for (; p + 3 < p1; p += 4) {
        int2 e0 = csr[p], e1 = csr[p + 1], e2 = csr[p + 2], e3 = csr[p + 3];
        float v0 = h[e0.x * 64 + lane];
        float v1 = h[e1.x * 64 + lane];
        float v2 = h[e2.x * 64 + lane];
        float v3 = h[e3.x * 64 + lane];
        acc += __int_as_float(e0.y) * v0;
        acc += __int_as_float(e1.y) * v1;
        acc += __int_as_float(e2.y) * v2;
        acc += __int_as_float(e3.y) * v3;
    }
    for (; p < p1; p++) {
        int2 e0 = csr[p];
        acc += __int_as_float(e0.y) * h[e0.x * 64 + lane];
    }
    agg[n * 64 + lane] = acc * dinv[n];
}

// ---- layer 1 transform: h1 = silu((agg + x*recip) @ W1 + b1), 16->16 ----
__global__ void k_xform1(const float* __restrict__ x, const float* __restrict__ agg,
                         const float* __restrict__ recip, const float* __restrict__ W,
                         const float* __restrict__ b, float* __restrict__ out, int N) {
    __shared__ float Ws[16 * 16];
    __shared__ float bs[16];
    if (threadIdx.x < 16 * 16) Ws[threadIdx.x] = W[threadIdx.x];
    if (threadIdx.x < 16) bs[threadIdx.x] = b[threadIdx.x];
    __syncthreads();
    int n = blockIdx.x * blockDim.x + threadIdx.x;
    if (n >= N) return;
    float r = recip[n];
    float y[16];
    const float4* x4 = (const float4*)(x + n * 16);
    const float4* a4 = (const float4*)(agg + n * 16);
#pragma unroll
    for (int j = 0; j < 4; j++) {
        float4 xv = x4[j], av = a4[j];
        y[4 * j + 0] = av.x + xv.x * r;
        y[4 * j + 1] = av.y + xv.y * r;
        y[4 * j + 2] = av.z + xv.z * r;
        y[4 * j + 3] = av.w + xv.w * r;
    }
    float4* o4 = (float4*)(out + n * 16);
#pragma unroll
    for (int oc = 0; oc < 4; oc++) {
        float4 acc = make_float4(bs[oc * 4 + 0], bs[oc * 4 + 1], bs[oc * 4 + 2], bs[oc * 4 + 3]);
#pragma unroll
        for (int d = 0; d < 16; d++) {
            float yd = y[d];
            acc.x += yd * Ws[d * 16 + oc * 4 + 0];
            acc.y += yd * Ws[d * 16 + oc * 4 + 1];
            acc.z += yd * Ws[d * 16 + oc * 4 + 2];
            acc.w += yd * Ws[d * 16 + oc * 4 + 3];
        }
        acc.x = silu_f(acc.x); acc.y = silu_f(acc.y);
        acc.z = silu_f(acc.z); acc.w = silu_f(acc.w);
        o4[oc] = acc;
    }
}

// ---- layer 2 transform: h2 = silu((agg + h1*recip) @ W2 + b2), 16->64 ----
__global__ void k_xform2(const float* __restrict__ h, const float* __restrict__ agg,
                         const float* __restrict__ recip, const float* __restrict__ W,
                         const float* __restrict__ b, float* __restrict__ out, int N) {
    __shared__ float Ws[16 * 64];
    __shared__ float bs[64];
    for (int i = threadIdx.x; i < 16 * 64; i += blockDim.x) Ws[i] = W[i];
    if (threadIdx.x < 64) bs[threadIdx.x] = b[threadIdx.x];
    __syncthreads();
    int n = blockIdx.x * blockDim.x + threadIdx.x;
    if (n >= N) return;
    float r = recip[n];
    float y[16];
    const float4* h4 = (const float4*)(h + n * 16);
    const float4* a4 = (const float4*)(agg + n * 16);
#pragma unroll
    for (int j = 0; j < 4; j++) {
        float4 hv = h4[j], av = a4[j];
        y[4 * j + 0] = av.x + hv.x * r;
        y[4 * j + 1] = av.y + hv.y * r;
        y[4 * j + 2] = av.z + hv.z * r;
        y[4 * j + 3] = av.w + hv.w * r;
    }
    float4* o4 = (float4*)(out + (long long)n * 64);
#pragma unroll
    for (int oc = 0; oc < 16; oc++) {
        float4 acc = make_float4(bs[oc * 4 + 0], bs[oc * 4 + 1], bs[oc * 4 + 2], bs[oc * 4 + 3]);
#pragma unroll
        for (int d = 0; d < 16; d++) {
            float yd = y[d];
            acc.x += yd * Ws[d * 64 + oc * 4 + 0];
            acc.y += yd * Ws[d * 64 + oc * 4 + 1];
            acc.z += yd * Ws[d * 64 + oc * 4 + 2];
            acc.w += yd * Ws[d * 64 + oc * 4 + 3];
        }
        acc.x = silu_f(acc.x); acc.y = silu_f(acc.y);
        acc.z = silu_f(acc.z); acc.w = silu_f(acc.w);
        o4[oc] = acc;
    }
}

// ---- layer 3 transform: h3 = silu((agg + h2*recip) @ W3 + b3), 64->256 ----
__global__ __launch_bounds__(256) void k_xform3(const float* __restrict__ h,
                                                const float* __restrict__ agg,
                                                const float* __restrict__ recip,
                                                const float* __restrict__ W,
                                                const float* __restrict__ b,
                                                float* __restrict__ out, int N) {
    __shared__ float4 Ws[64 * 64];  // [k][lane] -> W3[k*256 + lane*4 .. +3]  (64 KiB)
    for (int i = threadIdx.x; i < 64 * 64; i += 256) Ws[i] = ((const float4*)W)[i];
    __syncthreads();
    int wave = threadIdx.x >> 6;
    int lane = threadIdx.x & 63;
    float4 bv = ((const float4*)b)[lane];
    for (int base = blockIdx.x * 4; base < N; base += gridDim.x * 4) {
        int n = base + wave;
        if (n >= N) continue;  // wave-uniform
        float r = recip[n];
        float yv = agg[n * 64 + lane] + h[n * 64 + lane] * r;
        float4 acc = bv;
#pragma unroll
        for (int k = 0; k < 64; k++) {
            float yk = __shfl(yv, k, 64);
            float4 w = Ws[k * 64 + lane];
            acc.x += yk * w.x; acc.y += yk * w.y;
            acc.z += yk * w.z; acc.w += yk * w.w;
        }
        acc.x = silu_f(acc.x); acc.y = silu_f(acc.y);
        acc.z = silu_f(acc.z); acc.w = silu_f(acc.w);
        ((float4*)(out + (long long)n * 256))[lane] = acc;
    }
}

// ---- mean-pool per graph + MLP head, one block per graph ----
__global__ __launch_bounds__(256) void k_pool_mlp(const float* __restrict__ h3,
                                                  const int* __restrict__ batch, int N,
                                                  const float* __restrict__ L1,
                                                  const float* __restrict__ c1,
                                                  const float* __restrict__ L2,
                                                  const float* __restrict__ c2,
                                                  const float* __restrict__ L3,
                                                  const float* __restrict__ c3,
                                                  float* __restrict__ out) {
    __shared__ float pooled[256];
    __shared__ float z1[128];
    __shared__ float z2[64];
    int g = blockIdx.x;
    int lo = 0, hi = N;
    while (lo < hi) { int m = (lo + hi) >> 1; if (batch[m] < g) lo = m + 1; else hi = m; }
    int start = lo;
    hi = N;
    while (lo < hi) { int m = (lo + hi) >> 1; if (batch[m] < g + 1) lo = m + 1; else hi = m; }
    int end = lo;
    int t = threadIdx.x;
    float s = 0.0f;
    for (int i = start; i < end; i++) s += h3[(long long)i * 256 + t];
    int cnt = end - start;
    pooled[t] = s / (float)(cnt > 0 ? cnt : 1);
    __syncthreads();
    if (t < 128) {
        float acc = c1[t];
        for (int k = 0; k < 256; k++) acc += pooled[k] * L1[k * 128 + t];
        z1[t] = silu_f(acc);
    }
    __syncthreads();
    if (t < 64) {
        float acc = c2[t];
        for (int k = 0; k < 128; k++) acc += z1[k] * L2[k * 64 + t];
        z2[t] = silu_f(acc);
    }
    __syncthreads();
    if (t < 3) {
        float acc = c3[t];
        for (int k = 0; k < 64; k++) acc += z2[k] * L3[k * 3 + t];
        out[g * 3 + t] = acc;
    }
}

extern "C" void kernel_launch(void* const* d_in, const int* in_sizes, int n_in,
                              void* d_out, int out_size, void* d_ws, size_t ws_size,
                              hipStream_t stream) {
    const float* x     = (const float*)d_in[0];
    const int*   ei    = (const int*)d_in[1];
    const float* ea    = (const float*)d_in[2];
    const int*   batch = (const int*)d_in[3];
    const float* W1 = (const float*)d_in[4];
    const float* b1 = (const float*)d_in[5];
    const float* W2 = (const float*)d_in[6];
    const float* b2 = (const float*)d_in[7];
    const float* W3 = (const float*)d_in[8];
    const float* b3 = (const float*)d_in[9];
    const float* L1 = (const float*)d_in[10];
    const float* c1 = (const float*)d_in[11];
    const float* L2 = (const float*)d_in[12];
    const float* c2 = (const float*)d_in[13];
    const float* L3 = (const float*)d_in[14];
    const float* c3 = (const float*)d_in[15];
    float* out = (float*)d_out;

    const int N = in_sizes[0] / 16;
    const int E = in_sizes[2];
    const int G = out_size / 3;
    const int* src = ei;
    const int* dst = ei + E;
    const int nb = (N + 255) / 256;  // scan blocks (must be <= 512)

    char* ws = (char*)d_ws;
    size_t off = 0;
    auto alloc = [&](size_t bytes) -> void* {
        void* p = (void*)(ws + off);
        off += (bytes + 255) & ~(size_t)255;
        return p;
    };
    float* deg     = (float*)alloc((size_t)N * 4);
    float* dinv    = (float*)alloc((size_t)N * 4);
    float* recip   = (float*)alloc((size_t)N * 4);
    int*   cnt     = (int*)  alloc((size_t)N * 4);
    int*   offs    = (int*)  alloc((size_t)(N + 1) * 4);
    int*   cursors = (int*)  alloc((size_t)N * 4);
    int*   bsums   = (int*)  alloc(512 * 4);
    int2*  csr     = (int2*) alloc((size_t)E * 8);
    float* agg     = (float*)alloc((size_t)N * 64 * 4);
    float* h1      = (float*)alloc((size_t)N * 16 * 4);
    float* h2      = (float*)alloc((size_t)N * 64 * 4);
    float* h3      = (float*)alloc((size_t)N * 256 * 4);
    (void)ws_size;

    // ---- degree + counts, norms ----
    hipMemsetAsync(deg, 0, (size_t)N * 4, stream);
    hipMemsetAsync(cnt, 0, (size_t)N * 4, stream);
    k_deg_count<<<(E + 255) / 256, 256, 0, stream>>>(dst, ea, deg, cnt, E);
    k_norm<<<(N + 255) / 256, 256, 0, stream>>>(deg, dinv, recip, N);

    // ---- CSR build: scan counts -> offsets; fill entries ----
    k_scan1<<<nb, 256, 0, stream>>>(cnt, offs, bsums, N);
    k_scan2<<<1, 512, 0, stream>>>(bsums, nb);
    k_scan3<<<(N + 256) / 256, 256, 0, stream>>>(offs, bsums, N, E);
    hipMemcpyAsync(cursors, offs, (size_t)N * 4, hipMemcpyDeviceToDevice, stream);
    k_fill<<<(E + 255) / 256, 256, 0, stream>>>(src, dst, ea, dinv, cursors, csr, E);

    // ---- layer 1: gather x (16-d), transform 16->16 ----
    k_gather16<<<(N + 3) / 4, 256, 0, stream>>>(x, csr, offs, dinv, agg, N);
    k_xform1<<<(N + 255) / 256, 256, 0, stream>>>(x, agg, recip, W1, b1, h1, N);

    // ---- layer 2: gather h1 (16-d), transform 16->64 ----
    k_gather16<<<(N + 3) / 4, 256, 0, stream>>>(h1, csr, offs, dinv, agg, N);
    k_xform2<<<(N + 255) / 256, 256, 0, stream>>>(h1, agg, recip, W2, b2, h2, N);

    // ---- layer 3: gather h2 (64-d), transform 64->256 ----
    k_gather64<<<(N + 3) / 4, 256, 0, stream>>>(h2, csr, offs, dinv, agg, N);
    k_xform3<<<2048, 256, 0, stream>>>(h2, agg, recip, W3, b3, h3, N);

    // ---- mean-pool + MLP head ----
    k_pool_mlp<<<G, 256, 0, stream>>>(h3, batch, N, L1, c1, L2, c2, L3, c3, out);
}

// Round 3
// 1058.125 us; speedup vs baseline: 1.7501x; 1.3217x over previous
//
#include <hip/hip_runtime.h>
#include <math.h>

// ---------------------------------------------------------------------------
// GNN: 3x GCNConv(edge-weighted, self-loops) + SiLU, mean-pool, MLP.
// R1: CSR-by-dst + gather (no atomic scatter RMW).
// R2: parallel two-stage mean-pool (was: 64 blocks latency-bound, 400us/iter).
// ---------------------------------------------------------------------------

__device__ __forceinline__ float silu_f(float v) { return v / (1.0f + expf(-v)); }

// ---- deg (weighted, atomic) + integer in-degree count, one pass over edges ----
__global__ void k_deg_count(const int* __restrict__ dst, const float* __restrict__ ew,
                            float* __restrict__ deg, int* __restrict__ cnt, int E) {
    int e = blockIdx.x * blockDim.x + threadIdx.x;
    if (e < E) {
        int t = dst[e];
        atomicAdd(&deg[t], ew[e]);
        atomicAdd(&cnt[t], 1);
    }
}

// ---- dinv = 1/sqrt(deg+1), recip = 1/(deg+1) ----
__global__ void k_norm(const float* __restrict__ deg, float* __restrict__ dinv,
                       float* __restrict__ recip, int N) {
    int i = blockIdx.x * blockDim.x + threadIdx.x;
    if (i < N) {
        float d = deg[i] + 1.0f;
        dinv[i]  = 1.0f / sqrtf(d);
        recip[i] = 1.0f / d;
    }
}

// ---- exclusive scan of cnt -> offs ----
__global__ void k_scan1(const int* __restrict__ cnt, int* __restrict__ offs,
                        int* __restrict__ bsums, int N) {
    __shared__ int tmp[256];
    int t = threadIdx.x;
    int i = blockIdx.x * 256 + t;
    int v = (i < N) ? cnt[i] : 0;
    tmp[t] = v;
    __syncthreads();
#pragma unroll
    for (int o = 1; o < 256; o <<= 1) {
        int x = (t >= o) ? tmp[t - o] : 0;
        __syncthreads();
        tmp[t] += x;
        __syncthreads();
    }
    if (i < N) offs[i] = tmp[t] - v;
    if (t == 255) bsums[blockIdx.x] = tmp[t];
}

__global__ void k_scan2(int* __restrict__ bsums, int nb) {
    __shared__ int tmp[512];
    int t = threadIdx.x;
    int v = (t < nb) ? bsums[t] : 0;
    tmp[t] = v;
    __syncthreads();
#pragma unroll
    for (int o = 1; o < 512; o <<= 1) {
        int x = (t >= o) ? tmp[t - o] : 0;
        __syncthreads();
        tmp[t] += x;
        __syncthreads();
    }
    if (t < nb) bsums[t] = tmp[t] - v;
}

__global__ void k_scan3(int* __restrict__ offs, const int* __restrict__ bsums,
                        int N, int E) {
    int i = blockIdx.x * blockDim.x + threadIdx.x;
    if (i < N) offs[i] += bsums[i >> 8];
    if (i == N) offs[N] = E;
}

// ---- fill CSR: csr[p] = (src, ew*dinv[src]) packed ----
__global__ void k_fill(const int* __restrict__ src, const int* __restrict__ dst,
                       const float* __restrict__ ew, const float* __restrict__ dinv,
                       int* __restrict__ cursors, int2* __restrict__ csr, int E) {
    int e = blockIdx.x * blockDim.x + threadIdx.x;
    if (e >= E) return;
    int t = dst[e];
    int p = atomicAdd(&cursors[t], 1);
    int s = src[e];
    float w = ew[e] * dinv[s];
    csr[p] = make_int2(s, __float_as_int(w));
}

// ---- gather D=16: wave per node; 4 edge-groups x 16 dims ----
__global__ __launch_bounds__(256) void k_gather16(const float* __restrict__ h,
                                                  const int2* __restrict__ csr,
                                                  const int* __restrict__ offs,
                                                  const float* __restrict__ dinv,
                                                  float* __restrict__ agg, int N) {
    int n = blockIdx.x * 4 + (threadIdx.x >> 6);
    if (n >= N) return;
    int lane = threadIdx.x & 63;
    int d = lane & 15, eg = lane >> 4;
    int p0 = offs[n], p1 = offs[n + 1];
    float acc = 0.0f;
    for (int p = p0 + eg; p < p1; p += 4) {
        int2 ent = csr[p];
        acc += __int_as_float(ent.y) * h[ent.x * 16 + d];
    }
    acc += __shfl_down(acc, 32, 64);
    acc += __shfl_down(acc, 16, 64);
    if (lane < 16) agg[n * 16 + lane] = acc * dinv[n];
}

// ---- gather D=64: wave per node; lane = dim ----
__global__ __launch_bounds__(256) void k_gather64(const float* __restrict__ h,
                                                  const int2* __restrict__ csr,
                                                  const int* __restrict__ offs,
                                                  const float* __restrict__ dinv,
                                                  float* __restrict__ agg, int N) {
    int n = blockIdx.x * 4 + (threadIdx.x >> 6);
    if (n >= N) return;
    int lane = threadIdx.x & 63;
    int p0 = offs[n], p1 = offs[n + 1];
    float acc = 0.0f;
    int p = p0;
    for (; p + 3 < p1; p += 4) {
        int2 e0 = csr[p], e1 = csr[p + 1], e2 = csr[p + 2], e3 = csr[p + 3];
        float v0 = h[e0.x * 64 + lane];
        float v1 = h[e1.x * 64 + lane];
        float v2 = h[e2.x * 64 + lane];
        float v3 = h[e3.x * 64 + lane];
        acc += __int_as_float(e0.y) * v0;
        acc += __int_as_float(e1.y) * v1;
        acc += __int_as_float(e2.y) * v2;
        acc += __int_as_float(e3.y) * v3;
    }
    for (; p < p1; p++) {
        int2 e0 = csr[p];
        acc += __int_as_float(e0.y) * h[e0.x * 64 + lane];
    }
    agg[n * 64 + lane] = acc * dinv[n];
}

// ---- layer 1 transform: 16->16 ----
__global__ void k_xform1(const float* __restrict__ x, const float* __restrict__ agg,
                         const float* __restrict__ recip, const float* __restrict__ W,
                         const float* __restrict__ b, float* __restrict__ out, int N) {
    __shared__ float Ws[16 * 16];
    __shared__ float bs[16];
    if (threadIdx.x < 16 * 16) Ws[threadIdx.x] = W[threadIdx.x];
    if (threadIdx.x < 16) bs[threadIdx.x] = b[threadIdx.x];
    __syncthreads();
    int n = blockIdx.x * blockDim.x + threadIdx.x;
    if (n >= N) return;
    float r = recip[n];
    float y[16];
    const float4* x4 = (const float4*)(x + n * 16);
    const float4* a4 = (const float4*)(agg + n * 16);
#pragma unroll
    for (int j = 0; j < 4; j++) {
        float4 xv = x4[j], av = a4[j];
        y[4 * j + 0] = av.x + xv.x * r;
        y[4 * j + 1] = av.y + xv.y * r;
        y[4 * j + 2] = av.z + xv.z * r;
        y[4 * j + 3] = av.w + xv.w * r;
    }
    float4* o4 = (float4*)(out + n * 16);
#pragma unroll
    for (int oc = 0; oc < 4; oc++) {
        float4 acc = make_float4(bs[oc * 4 + 0], bs[oc * 4 + 1], bs[oc * 4 + 2], bs[oc * 4 + 3]);
#pragma unroll
        for (int d = 0; d < 16; d++) {
            float yd = y[d];
            acc.x += yd * Ws[d * 16 + oc * 4 + 0];
            acc.y += yd * Ws[d * 16 + oc * 4 + 1];
            acc.z += yd * Ws[d * 16 + oc * 4 + 2];
            acc.w += yd * Ws[d * 16 + oc * 4 + 3];
        }
        acc.x = silu_f(acc.x); acc.y = silu_f(acc.y);
        acc.z = silu_f(acc.z); acc.w = silu_f(acc.w);
        o4[oc] = acc;
    }
}

// ---- layer 2 transform: 16->64 ----
__global__ void k_xform2(const float* __restrict__ h, const float* __restrict__ agg,
                         const float* __restrict__ recip, const float* __restrict__ W,
                         const float* __restrict__ b, float* __restrict__ out, int N) {
    __shared__ float Ws[16 * 64];
    __shared__ float bs[64];
    for (int i = threadIdx.x; i < 16 * 64; i += blockDim.x) Ws[i] = W[i];
    if (threadIdx.x < 64) bs[threadIdx.x] = b[threadIdx.x];
    __syncthreads();
    int n = blockIdx.x * blockDim.x + threadIdx.x;
    if (n >= N) return;
    float r = recip[n];
    float y[16];
    const float4* h4 = (const float4*)(h + n * 16);
    const float4* a4 = (const float4*)(agg + n * 16);
#pragma unroll
    for (int j = 0; j < 4; j++) {
        float4 hv = h4[j], av = a4[j];
        y[4 * j + 0] = av.x + hv.x * r;
        y[4 * j + 1] = av.y + hv.y * r;
        y[4 * j + 2] = av.z + hv.z * r;
        y[4 * j + 3] = av.w + hv.w * r;
    }
    float4* o4 = (float4*)(out + (long long)n * 64);
#pragma unroll
    for (int oc = 0; oc < 16; oc++) {
        float4 acc = make_float4(bs[oc * 4 + 0], bs[oc * 4 + 1], bs[oc * 4 + 2], bs[oc * 4 + 3]);
#pragma unroll
        for (int d = 0; d < 16; d++) {
            float yd = y[d];
            acc.x += yd * Ws[d * 64 + oc * 4 + 0];
            acc.y += yd * Ws[d * 64 + oc * 4 + 1];
            acc.z += yd * Ws[d * 64 + oc * 4 + 2];
            acc.w += yd * Ws[d * 64 + oc * 4 + 3];
        }
        acc.x = silu_f(acc.x); acc.y = silu_f(acc.y);
        acc.z = silu_f(acc.z); acc.w = silu_f(acc.w);
        o4[oc] = acc;
    }
}

// ---- layer 3 transform: 64->256, wave per node ----
__global__ __launch_bounds__(256) void k_xform3(const float* __restrict__ h,
                                                const float* __restrict__ agg,
                                                const float* __restrict__ recip,
                                                const float* __restrict__ W,
                                                const float* __restrict__ b,
                                                float* __restrict__ out, int N) {
    __shared__ float4 Ws[64 * 64];  // 64 KiB
    for (int i = threadIdx.x; i < 64 * 64; i += 256) Ws[i] = ((const float4*)W)[i];
    __syncthreads();
    int wave = threadIdx.x >> 6;
    int lane = threadIdx.x & 63;
    float4 bv = ((const float4*)b)[lane];
    for (int base = blockIdx.x * 4; base < N; base += gridDim.x * 4) {
        int n = base + wave;
        if (n >= N) continue;
        float r = recip[n];
        float yv = agg[n * 64 + lane] + h[n * 64 + lane] * r;
        float4 acc = bv;
#pragma unroll
        for (int k = 0; k < 64; k++) {
            float yk = __shfl(yv, k, 64);
            float4 w = Ws[k * 64 + lane];
            acc.x += yk * w.x; acc.y += yk * w.y;
            acc.z += yk * w.z; acc.w += yk * w.w;
        }
        acc.x = silu_f(acc.x); acc.y = silu_f(acc.y);
        acc.z = silu_f(acc.z); acc.w = silu_f(acc.w);
        ((float4*)(out + (long long)n * 256))[lane] = acc;
    }
}

// ---- graph boundaries: bounds[g] = lower_bound(batch, g); bounds[G] = N ----
__global__ void k_bounds(const int* __restrict__ batch, int* __restrict__ bounds,
                         int N, int G) {
    int g = blockIdx.x * blockDim.x + threadIdx.x;
    if (g > G) return;
    if (g == G) { bounds[G] = N; return; }
    int lo = 0, hi = N;
    while (lo < hi) { int m = (lo + hi) >> 1; if (batch[m] < g) lo = m + 1; else hi = m; }
    bounds[g] = lo;
}

// ---- pool stage 1: grid = G*C blocks; block (g,c) sums its node chunk ----
#define POOL_C 32
__global__ __launch_bounds__(256) void k_pool_partial(const float* __restrict__ h3,
                                                      const int* __restrict__ bounds,
                                                      float* __restrict__ partial) {
    int g = blockIdx.x / POOL_C;
    int c = blockIdx.x % POOL_C;
    int s = bounds[g], e = bounds[g + 1];
    int len = e - s;
    int cs = s + (int)((long long)len * c / POOL_C);
    int ce = s + (int)((long long)len * (c + 1) / POOL_C);
    int t = threadIdx.x;
    float acc = 0.0f;
    for (int i = cs; i < ce; i++) acc += h3[(long long)i * 256 + t];
    partial[(long long)blockIdx.x * 256 + t] = acc;
}

// ---- pool stage 2 + MLP: one block per graph ----
__global__ __launch_bounds__(256) void k_mlp(const float* __restrict__ partial,
                                             const int* __restrict__ bounds,
                                             const float* __restrict__ L1,
                                             const float* __restrict__ c1,
                                             const float* __restrict__ L2,
                                             const float* __restrict__ c2,
                                             const float* __restrict__ L3,
                                             const float* __restrict__ c3,
                                             float* __restrict__ out) {
    __shared__ float pooled[256];
    __shared__ float z1[128];
    __shared__ float z2[64];
    int g = blockIdx.x;
    int t = threadIdx.x;
    int cnt = bounds[g + 1] - bounds[g];
    float s = 0.0f;
    for (int c = 0; c < POOL_C; c++) s += partial[((long long)g * POOL_C + c) * 256 + t];
    pooled[t] = s / (float)(cnt > 0 ? cnt : 1);
    __syncthreads();
    if (t < 128) {
        float acc = c1[t];
        for (int k = 0; k < 256; k++) acc += pooled[k] * L1[k * 128 + t];
        z1[t] = silu_f(acc);
    }
    __syncthreads();
    if (t < 64) {
        float acc = c2[t];
        for (int k = 0; k < 128; k++) acc += z1[k] * L2[k * 64 + t];
        z2[t] = silu_f(acc);
    }
    __syncthreads();
    if (t < 3) {
        float acc = c3[t];
        for (int k = 0; k < 64; k++) acc += z2[k] * L3[k * 3 + t];
        out[g * 3 + t] = acc;
    }
}

extern "C" void kernel_launch(void* const* d_in, const int* in_sizes, int n_in,
                              void* d_out, int out_size, void* d_ws, size_t ws_size,
                              hipStream_t stream) {
    const float* x     = (const float*)d_in[0];
    const int*   ei    = (const int*)d_in[1];
    const float* ea    = (const float*)d_in[2];
    const int*   batch = (const int*)d_in[3];
    const float* W1 = (const float*)d_in[4];
    const float* b1 = (const float*)d_in[5];
    const float* W2 = (const float*)d_in[6];
    const float* b2 = (const float*)d_in[7];
    const float* W3 = (const float*)d_in[8];
    const float* b3 = (const float*)d_in[9];
    const float* L1 = (const float*)d_in[10];
    const float* c1 = (const float*)d_in[11];
    const float* L2 = (const float*)d_in[12];
    const float* c2 = (const float*)d_in[13];
    const float* L3 = (const float*)d_in[14];
    const float* c3 = (const float*)d_in[15];
    float* out = (float*)d_out;

    const int N = in_sizes[0] / 16;
    const int E = in_sizes[2];
    const int G = out_size / 3;
    const int* src = ei;
    const int* dst = ei + E;
    const int nb = (N + 255) / 256;

    char* ws = (char*)d_ws;
    size_t off = 0;
    auto alloc = [&](size_t bytes) -> void* {
        void* p = (void*)(ws + off);
        off += (bytes + 255) & ~(size_t)255;
        return p;
    };
    float* deg     = (float*)alloc((size_t)N * 4);
    float* dinv    = (float*)alloc((size_t)N * 4);
    float* recip   = (float*)alloc((size_t)N * 4);
    int*   cnt     = (int*)  alloc((size_t)N * 4);
    int*   offs    = (int*)  alloc((size_t)(N + 1) * 4);
    int*   cursors = (int*)  alloc((size_t)N * 4);
    int*   bsums   = (int*)  alloc(512 * 4);
    int2*  csr     = (int2*) alloc((size_t)E * 8);
    float* agg     = (float*)alloc((size_t)N * 64 * 4);
    float* h1      = (float*)alloc((size_t)N * 16 * 4);
    float* h2      = (float*)alloc((size_t)N * 64 * 4);
    float* h3      = (float*)alloc((size_t)N * 256 * 4);
    (void)ws_size;
    // reuse (free after their producers/consumers):
    float* partial = agg;          // G*POOL_C*256 floats = 8 MB <= 25.6 MB  (agg dead after xform3)
    int*   bounds  = cursors;      // G+1 ints              (cursors dead after k_fill)

    // ---- degree + counts, norms ----
    hipMemsetAsync(deg, 0, (size_t)N * 4, stream);
    hipMemsetAsync(cnt, 0, (size_t)N * 4, stream);
    k_deg_count<<<(E + 255) / 256, 256, 0, stream>>>(dst, ea, deg, cnt, E);
    k_norm<<<(N + 255) / 256, 256, 0, stream>>>(deg, dinv, recip, N);

    // ---- CSR build ----
    k_scan1<<<nb, 256, 0, stream>>>(cnt, offs, bsums, N);
    k_scan2<<<1, 512, 0, stream>>>(bsums, nb);
    k_scan3<<<(N + 256) / 256, 256, 0, stream>>>(offs, bsums, N, E);
    hipMemcpyAsync(cursors, offs, (size_t)N * 4, hipMemcpyDeviceToDevice, stream);
    k_fill<<<(E + 255) / 256, 256, 0, stream>>>(src, dst, ea, dinv, cursors, csr, E);

    // ---- layer 1 ----
    k_gather16<<<(N + 3) / 4, 256, 0, stream>>>(x, csr, offs, dinv, agg, N);
    k_xform1<<<(N + 255) / 256, 256, 0, stream>>>(x, agg, recip, W1, b1, h1, N);

    // ---- layer 2 ----
    k_gather16<<<(N + 3) / 4, 256, 0, stream>>>(h1, csr, offs, dinv, agg, N);
    k_xform2<<<(N + 255) / 256, 256, 0, stream>>>(h1, agg, recip, W2, b2, h2, N);

    // ---- layer 3 ----
    k_gather64<<<(N + 3) / 4, 256, 0, stream>>>(h2, csr, offs, dinv, agg, N);
    k_xform3<<<2048, 256, 0, stream>>>(h2, agg, recip, W3, b3, h3, N);

    // ---- pool (two-stage, parallel) + MLP head ----
    k_bounds<<<1, 128, 0, stream>>>(batch, bounds, N, G);
    k_pool_partial<<<G * POOL_C, 256, 0, stream>>>(h3, bounds, partial);
    k_mlp<<<G, 256, 0, stream>>>(partial, bounds, L1, c1, L2, c2, L3, c3, out);
}

// Round 4
// 825.136 us; speedup vs baseline: 2.2443x; 1.2824x over previous
//
#include <hip/hip_runtime.h>
#include <math.h>

// ---------------------------------------------------------------------------
// GNN: 3x GCNConv(edge-weighted, self-loops) + SiLU, mean-pool, MLP.
// R1: CSR-by-dst + gather (no atomic scatter RMW).
// R2: parallel two-stage mean-pool.
// R3: single atomic pass (rank trick) -> atomic-free fill; deg from CSR rows
//     (no float atomics); scaled-feature trick h'=h*dinv removes csr rescale.
// ---------------------------------------------------------------------------

__device__ __forceinline__ float silu_f(float v) { return v / (1.0f + expf(-v)); }

// ---- pass A: cnt atomics + per-edge rank within its dst row ----
__global__ void k_cnt_rank(const int* __restrict__ dst, int* __restrict__ cnt,
                           int* __restrict__ rank, int E) {
    int e = blockIdx.x * blockDim.x + threadIdx.x;
    if (e < E) rank[e] = atomicAdd(&cnt[dst[e]], 1);
}

// ---- exclusive scan of cnt -> offs ----
__global__ void k_scan1(const int* __restrict__ cnt, int* __restrict__ offs,
                        int* __restrict__ bsums, int N) {
    __shared__ int tmp[256];
    int t = threadIdx.x;
    int i = blockIdx.x * 256 + t;
    int v = (i < N) ? cnt[i] : 0;
    tmp[t] = v;
    __syncthreads();
#pragma unroll
    for (int o = 1; o < 256; o <<= 1) {
        int x = (t >= o) ? tmp[t - o] : 0;
        __syncthreads();
        tmp[t] += x;
        __syncthreads();
    }
    if (i < N) offs[i] = tmp[t] - v;
    if (t == 255) bsums[blockIdx.x] = tmp[t];
}

__global__ void k_scan2(int* __restrict__ bsums, int nb) {
    __shared__ int tmp[512];
    int t = threadIdx.x;
    int v = (t < nb) ? bsums[t] : 0;
    tmp[t] = v;
    __syncthreads();
#pragma unroll
    for (int o = 1; o < 512; o <<= 1) {
        int x = (t >= o) ? tmp[t - o] : 0;
        __syncthreads();
        tmp[t] += x;
        __syncthreads();
    }
    if (t < nb) bsums[t] = tmp[t] - v;
}

__global__ void k_scan3(int* __restrict__ offs, const int* __restrict__ bsums,
                        int N, int E) {
    int i = blockIdx.x * blockDim.x + threadIdx.x;
    if (i < N) offs[i] += bsums[i >> 8];
    if (i == N) offs[N] = E;
}

// ---- pass B: atomic-free CSR fill; csr[p] = (src, raw ew) ----
__global__ void k_fill2(const int* __restrict__ src, const int* __restrict__ dst,
                        const float* __restrict__ ew, const int* __restrict__ rank,
                        const int* __restrict__ offs, int2* __restrict__ csr, int E) {
    int e = blockIdx.x * blockDim.x + threadIdx.x;
    if (e >= E) return;
    int p = offs[dst[e]] + rank[e];
    csr[p] = make_int2(src[e], __float_as_int(ew[e]));
}

// ---- per-node: deg = sum(ew over row); dinv = 1/sqrt(deg+1) ----
__global__ void k_rowsum(const int2* __restrict__ csr, const int* __restrict__ offs,
                         float* __restrict__ dinv, int N) {
    int n = blockIdx.x * blockDim.x + threadIdx.x;
    if (n >= N) return;
    int p0 = offs[n], p1 = offs[n + 1];
    float d = 1.0f;  // self-loop
    for (int p = p0; p < p1; p++) d += __int_as_float(csr[p].y);
    dinv[n] = 1.0f / sqrtf(d);
}

// ---- x' = x * dinv[n], float4 per thread ----
__global__ void k_xscale(const float* __restrict__ x, const float* __restrict__ dinv,
                         float* __restrict__ xp, int N) {
    int i = blockIdx.x * blockDim.x + threadIdx.x;   // over N*4 float4s
    if (i >= N * 4) return;
    float s = dinv[i >> 2];
    float4 v = ((const float4*)x)[i];
    v.x *= s; v.y *= s; v.z *= s; v.w *= s;
    ((float4*)xp)[i] = v;
}

// ---- gather D=16: wave per node; 4 edge-groups x 16 dims ----
// agg[n] = dinv[n] * sum_e ew_e * h'[src_e]   (h' pre-scaled by dinv[src])
__global__ __launch_bounds__(256) void k_gather16(const float* __restrict__ h,
                                                  const int2* __restrict__ csr,
                                                  const int* __restrict__ offs,
                                                  const float* __restrict__ dinv,
                                                  float* __restrict__ agg, int N) {
    int n = blockIdx.x * 4 + (threadIdx.x >> 6);
    n = __builtin_amdgcn_readfirstlane(n);           // wave-uniform -> scalar loads
    if (n >= N) return;
    int lane = threadIdx.x & 63;
    int d = lane & 15, eg = lane >> 4;
    int p0 = offs[n], p1 = offs[n + 1];
    float acc = 0.0f;
    for (int p = p0 + eg; p < p1; p += 4) {
        int2 ent = csr[p];
        acc += __int_as_float(ent.y) * h[ent.x * 16 + d];
    }
    acc += __shfl_down(acc, 32, 64);
    acc += __shfl_down(acc, 16, 64);
    if (lane < 16) agg[n * 16 + lane] = acc * dinv[n];
}

// ---- gather D=64: wave per node; lane = dim ----
__global__ __launch_bounds__(256) void k_gather64(const float* __restrict__ h,
                                                  const int2* __restrict__ csr,
                                                  const int* __restrict__ offs,
                                                  const float* __restrict__ dinv,
                                                  float* __restrict__ agg, int N) {
    int n = blockIdx.x * 4 + (threadIdx.x >> 6);
    n = __builtin_amdgcn_readfirstlane(n);           // wave-uniform -> scalar loads
    if (n >= N) return;
    int lane = threadIdx.x & 63;
    int p0 = offs[n], p1 = offs[n + 1];
    const int2* row = csr + p0;
    int len = p1 - p0;
    float acc = 0.0f;
    int j = 0;
    for (; j + 3 < len; j += 4) {
        int2 e0 = row[j], e1 = row[j + 1], e2 = row[j + 2], e3 = row[j + 3];
        float v0 = h[e0.x * 64 + lane];
        float v1 = h[e1.x * 64 + lane];
        float v2 = h[e2.x * 64 + lane];
        float v3 = h[e3.x * 64 + lane];
        acc += __int_as_float(e0.y) * v0;
        acc += __int_as_float(e1.y) * v1;
        acc += __int_as_float(e2.y) * v2;
        acc += __int_as_float(e3.y) * v3;
    }
    for (; j < len; j++) {
        int2 e0 = row[j];
        acc += __int_as_float(e0.y) * h[e0.x * 64 + lane];
    }
    agg[n * 64 + lane] = acc * dinv[n];
}

// ---- layer 1 transform: 16->16; in/out are dinv-scaled features ----
// y = agg + xp*dinv (= agg + x*recip);  out = silu(y@W+b) * dinv
__global__ void k_xform1(const float* __restrict__ xp, const float* __restrict__ agg,
                         const float* __restrict__ dinv, const float* __restrict__ W,
                         const float* __restrict__ b, float* __restrict__ out, int N) {
    __shared__ float Ws[16 * 16];
    __shared__ float bs[16];
    if (threadIdx.x < 16 * 16) Ws[threadIdx.x] = W[threadIdx.x];
    if (threadIdx.x < 16) bs[threadIdx.x] = b[threadIdx.x];
    __syncthreads();
    int n = blockIdx.x * blockDim.x + threadIdx.x;
    if (n >= N) return;
    float dv = dinv[n];
    float y[16];
    const float4* x4 = (const float4*)(xp + n * 16);
    const float4* a4 = (const float4*)(agg + n * 16);
#pragma unroll
    for (int j = 0; j < 4; j++) {
        float4 xv = x4[j], av = a4[j];
        y[4 * j + 0] = av.x + xv.x * dv;
        y[4 * j + 1] = av.y + xv.y * dv;
        y[4 * j + 2] = av.z + xv.z * dv;
        y[4 * j + 3] = av.w + xv.w * dv;
    }
    float4* o4 = (float4*)(out + n * 16);
#pragma unroll
    for (int oc = 0; oc < 4; oc++) {
        float4 acc = make_float4(bs[oc * 4 + 0], bs[oc * 4 + 1], bs[oc * 4 + 2], bs[oc * 4 + 3]);
#pragma unroll
        for (int d = 0; d < 16; d++) {
            float yd = y[d];
            acc.x += yd * Ws[d * 16 + oc * 4 + 0];
            acc.y += yd * Ws[d * 16 + oc * 4 + 1];
            acc.z += yd * Ws[d * 16 + oc * 4 + 2];
            acc.w += yd * Ws[d * 16 + oc * 4 + 3];
        }
        acc.x = silu_f(acc.x) * dv; acc.y = silu_f(acc.y) * dv;
        acc.z = silu_f(acc.z) * dv; acc.w = silu_f(acc.w) * dv;
        o4[oc] = acc;
    }
}

// ---- layer 2 transform: 16->64; scaled in/out ----
__global__ void k_xform2(const float* __restrict__ h, const float* __restrict__ agg,
                         const float* __restrict__ dinv, const float* __restrict__ W,
                         const float* __restrict__ b, float* __restrict__ out, int N) {
    __shared__ float Ws[16 * 64];
    __shared__ float bs[64];
    for (int i = threadIdx.x; i < 16 * 64; i += blockDim.x) Ws[i] = W[i];
    if (threadIdx.x < 64) bs[threadIdx.x] = b[threadIdx.x];
    __syncthreads();
    int n = blockIdx.x * blockDim.x + threadIdx.x;
    if (n >= N) return;
    float dv = dinv[n];
    float y[16];
    const float4* h4 = (const float4*)(h + n * 16);
    const float4* a4 = (const float4*)(agg + n * 16);
#pragma unroll
    for (int j = 0; j < 4; j++) {
        float4 hv = h4[j], av = a4[j];
        y[4 * j + 0] = av.x + hv.x * dv;
        y[4 * j + 1] = av.y + hv.y * dv;
        y[4 * j + 2] = av.z + hv.z * dv;
        y[4 * j + 3] = av.w + hv.w * dv;
    }
    float4* o4 = (float4*)(out + (long long)n * 64);
#pragma unroll
    for (int oc = 0; oc < 16; oc++) {
        float4 acc = make_float4(bs[oc * 4 + 0], bs[oc * 4 + 1], bs[oc * 4 + 2], bs[oc * 4 + 3]);
#pragma unroll
        for (int d = 0; d < 16; d++) {
            float yd = y[d];
            acc.x += yd * Ws[d * 64 + oc * 4 + 0];
            acc.y += yd * Ws[d * 64 + oc * 4 + 1];
            acc.z += yd * Ws[d * 64 + oc * 4 + 2];
            acc.w += yd * Ws[d * 64 + oc * 4 + 3];
        }
        acc.x = silu_f(acc.x) * dv; acc.y = silu_f(acc.y) * dv;
        acc.z = silu_f(acc.z) * dv; acc.w = silu_f(acc.w) * dv;
        o4[oc] = acc;
    }
}

// ---- layer 3 transform: 64->256, wave per node; UNSCALED output (pool input) ----
__global__ __launch_bounds__(256) void k_xform3(const float* __restrict__ h,
                                                const float* __restrict__ agg,
                                                const float* __restrict__ dinv,
                                                const float* __restrict__ W,
                                                const float* __restrict__ b,
                                                float* __restrict__ out, int N) {
    __shared__ float4 Ws[64 * 64];  // 64 KiB
    for (int i = threadIdx.x; i < 64 * 64; i += 256) Ws[i] = ((const float4*)W)[i];
    __syncthreads();
    int wave = threadIdx.x >> 6;
    int lane = threadIdx.x & 63;
    float4 bv = ((const float4*)b)[lane];
    for (int base = blockIdx.x * 4; base < N; base += gridDim.x * 4) {
        int n = base + wave;
        if (n >= N) continue;
        float dv = dinv[n];
        float yv = agg[n * 64 + lane] + h[n * 64 + lane] * dv;
        float4 acc = bv;
#pragma unroll
        for (int k = 0; k < 64; k++) {
            float yk = __shfl(yv, k, 64);
            float4 w = Ws[k * 64 + lane];
            acc.x += yk * w.x; acc.y += yk * w.y;
            acc.z += yk * w.z; acc.w += yk * w.w;
        }
        acc.x = silu_f(acc.x); acc.y = silu_f(acc.y);
        acc.z = silu_f(acc.z); acc.w = silu_f(acc.w);
        ((float4*)(out + (long long)n * 256))[lane] = acc;
    }
}

// ---- graph boundaries ----
__global__ void k_bounds(const int* __restrict__ batch, int* __restrict__ bounds,
                         int N, int G) {
    int g = blockIdx.x * blockDim.x + threadIdx.x;
    if (g > G) return;
    if (g == G) { bounds[G] = N; return; }
    int lo = 0, hi = N;
    while (lo < hi) { int m = (lo + hi) >> 1; if (batch[m] < g) lo = m + 1; else hi = m; }
    bounds[g] = lo;
}

// ---- pool stage 1 ----
#define POOL_C 32
__global__ __launch_bounds__(256) void k_pool_partial(const float* __restrict__ h3,
                                                      const int* __restrict__ bounds,
                                                      float* __restrict__ partial) {
    int g = blockIdx.x / POOL_C;
    int c = blockIdx.x % POOL_C;
    int s = bounds[g], e = bounds[g + 1];
    int len = e - s;
    int cs = s + (int)((long long)len * c / POOL_C);
    int ce = s + (int)((long long)len * (c + 1) / POOL_C);
    int t = threadIdx.x;
    float acc = 0.0f;
    for (int i = cs; i < ce; i++) acc += h3[(long long)i * 256 + t];
    partial[(long long)blockIdx.x * 256 + t] = acc;
}

// ---- pool stage 2 + MLP ----
__global__ __launch_bounds__(256) void k_mlp(const float* __restrict__ partial,
                                             const int* __restrict__ bounds,
                                             const float* __restrict__ L1,
                                             const float* __restrict__ c1,
                                             const float* __restrict__ L2,
                                             const float* __restrict__ c2,
                                             const float* __restrict__ L3,
                                             const float* __restrict__ c3,
                                             float* __restrict__ out) {
    __shared__ float pooled[256];
    __shared__ float z1[128];
    __shared__ float z2[64];
    int g = blockIdx.x;
    int t = threadIdx.x;
    int cnt = bounds[g + 1] - bounds[g];
    float s = 0.0f;
    for (int c = 0; c < POOL_C; c++) s += partial[((long long)g * POOL_C + c) * 256 + t];
    pooled[t] = s / (float)(cnt > 0 ? cnt : 1);
    __syncthreads();
    if (t < 128) {
        float acc = c1[t];
        for (int k = 0; k < 256; k++) acc += pooled[k] * L1[k * 128 + t];
        z1[t] = silu_f(acc);
    }
    __syncthreads();
    if (t < 64) {
        float acc = c2[t];
        for (int k = 0; k < 128; k++) acc += z1[k] * L2[k * 64 + t];
        z2[t] = silu_f(acc);
    }
    __syncthreads();
    if (t < 3) {
        float acc = c3[t];
        for (int k = 0; k < 64; k++) acc += z2[k] * L3[k * 3 + t];
        out[g * 3 + t] = acc;
    }
}

extern "C" void kernel_launch(void* const* d_in, const int* in_sizes, int n_in,
                              void* d_out, int out_size, void* d_ws, size_t ws_size,
                              hipStream_t stream) {
    const float* x     = (const float*)d_in[0];
    const int*   ei    = (const int*)d_in[1];
    const float* ea    = (const float*)d_in[2];
    const int*   batch = (const int*)d_in[3];
    const float* W1 = (const float*)d_in[4];
    const float* b1 = (const float*)d_in[5];
    const float* W2 = (const float*)d_in[6];
    const float* b2 = (const float*)d_in[7];
    const float* W3 = (const float*)d_in[8];
    const float* b3 = (const float*)d_in[9];
    const float* L1 = (const float*)d_in[10];
    const float* c1 = (const float*)d_in[11];
    const float* L2 = (const float*)d_in[12];
    const float* c2 = (const float*)d_in[13];
    const float* L3 = (const float*)d_in[14];
    const float* c3 = (const float*)d_in[15];
    float* out = (float*)d_out;

    const int N = in_sizes[0] / 16;
    const int E = in_sizes[2];
    const int G = out_size / 3;
    const int* src = ei;
    const int* dst = ei + E;
    const int nb = (N + 255) / 256;

    char* ws = (char*)d_ws;
    size_t off = 0;
    auto alloc = [&](size_t bytes) -> void* {
        void* p = (void*)(ws + off);
        off += (bytes + 255) & ~(size_t)255;
        return p;
    };
    float* dinv   = (float*)alloc((size_t)N * 4);
    int*   cnt    = (int*)  alloc((size_t)N * 4);
    int*   offs   = (int*)  alloc((size_t)(N + 1) * 4);
    int*   bsums  = (int*)  alloc(512 * 4);
    int*   bounds = (int*)  alloc((size_t)(G + 1) * 4);
    int2*  csr    = (int2*) alloc((size_t)E * 8);
    float* agg    = (float*)alloc((size_t)N * 64 * 4);   // also: rank (E ints), partial (8MB)
    float* h1s    = (float*)alloc((size_t)N * 16 * 4);
    float* h2s    = (float*)alloc((size_t)N * 64 * 4);
    float* h3     = (float*)alloc((size_t)N * 256 * 4);  // first 6.4MB doubles as xp
    (void)ws_size;
    int*   rank    = (int*)agg;     // dead before agg first written (gather1)
    float* partial = agg;           // dead after xform3 reads agg
    float* xp      = h3;            // dead before xform3 writes h3

    // ---- pass A: counts + ranks (the ONLY atomic pass) ----
    hipMemsetAsync(cnt, 0, (size_t)N * 4, stream);
    k_cnt_rank<<<(E + 255) / 256, 256, 0, stream>>>(dst, cnt, rank, E);

    // ---- scan -> offs ----
    k_scan1<<<nb, 256, 0, stream>>>(cnt, offs, bsums, N);
    k_scan2<<<1, 512, 0, stream>>>(bsums, nb);
    k_scan3<<<(N + 256) / 256, 256, 0, stream>>>(offs, bsums, N, E);

    // ---- pass B: atomic-free fill; then per-row degree -> dinv ----
    k_fill2<<<(E + 255) / 256, 256, 0, stream>>>(src, dst, ea, rank, offs, csr, E);
    k_rowsum<<<(N + 255) / 256, 256, 0, stream>>>(csr, offs, dinv, N);
    k_xscale<<<(N * 4 + 255) / 256, 256, 0, stream>>>(x, dinv, xp, N);

    // ---- layer 1 ----
    k_gather16<<<(N + 3) / 4, 256, 0, stream>>>(xp, csr, offs, dinv, agg, N);
    k_xform1<<<(N + 255) / 256, 256, 0, stream>>>(xp, agg, dinv, W1, b1, h1s, N);

    // ---- layer 2 ----
    k_gather16<<<(N + 3) / 4, 256, 0, stream>>>(h1s, csr, offs, dinv, agg, N);
    k_xform2<<<(N + 255) / 256, 256, 0, stream>>>(h1s, agg, dinv, W2, b2, h2s, N);

    // ---- layer 3 ----
    k_gather64<<<(N + 3) / 4, 256, 0, stream>>>(h2s, csr, offs, dinv, agg, N);
    k_xform3<<<2048, 256, 0, stream>>>(h2s, agg, dinv, W3, b3, h3, N);

    // ---- pool + MLP head ----
    k_bounds<<<1, 128, 0, stream>>>(batch, bounds, N, G);
    k_pool_partial<<<G * POOL_C, 256, 0, stream>>>(h3, bounds, partial);
    k_mlp<<<G, 256, 0, stream>>>(partial, bounds, L1, c1, L2, c2, L3, c3, out);
}